// Round 11
// baseline (101.435 us; speedup 1.0000x reference)
//
#include <hip/hip_runtime.h>
#include <math.h>

#define BB 32
#define TT 512
#define HH 1024
#define DD 256
#define CC 52
#define NTT 8
#define NEE 24
#define AA 36
#define STARTT 50
#define STOPP 51
#define NCH 16     // chunks per batch
#define CL 32      // chunk length (steps)

// workspace float offsets
static const size_t OFF_WAT    = 0;        // 2048*36 = 73728, layout [h][a]
static const size_t OFF_BA     = 73728;    // 64
static const size_t OFF_ESTART = 73792;    // 64
static const size_t OFF_ESTOP  = 73856;    // 64
static const size_t OFF_BEFF   = 73920;    // 64
static const size_t OFF_EA     = 73984;    // 2048 u32 = 64x64 bf16 A-matrix (E64^T)
static const size_t OFF_WPACK  = 76032;    // 32768 u32 (128KB) MFMA-B layout W_eff
static const size_t OFF_FEATS  = 108800;   // 16384*52
static const size_t OFF_EF64   = 960768;   // 16384*64
static const size_t OFF_RMAT   = 2009344;  // 32*16*2048 u32 chunk matrices (4MB)
static const size_t OFF_TVEC   = 4106496;  // 32*8*1024
static const size_t OFF_EVEC   = 4368640;  // 32*24*1024
static const size_t OFF_TLOG   = 5155072;  // 32*8*36
static const size_t OFF_ELOG   = 5164288;  // 32*24*36
static const size_t OFF_LOSS   = 5191936;  // 32
static const size_t OFF_RED    = 5191968;  // u32[2]: [0]=loss counter

typedef __bf16 bf16x8 __attribute__((ext_vector_type(8)));
typedef float f32x4 __attribute__((ext_vector_type(4)));
typedef unsigned int uint4v __attribute__((ext_vector_type(4)));

union U4B { uint4v u; bf16x8 b; };

typedef const __attribute__((address_space(1))) void gvoid_t;
typedef __attribute__((address_space(3))) void lvoid_t;
#define GLOAD16(g, l) __builtin_amdgcn_global_load_lds((gvoid_t*)(g), (lvoid_t*)(l), 16, 0, 0)

static __device__ __forceinline__ unsigned int rne_bf16(float x) {
    unsigned int u = __float_as_uint(x);
    u += 0x7FFFu + ((u >> 16) & 1u);
    return u >> 16;
}

// ================= K1: WPACK + BEFF only (the true feats prerequisites) =================
__global__ __launch_bounds__(256) void k1_pack(
    const float* __restrict__ fc_W1, const float* __restrict__ fc_b1,
    const float* __restrict__ fc_W2, const float* __restrict__ fc_b2,
    float* __restrict__ ws)
{
    int bid = blockIdx.x, tid = threadIdx.x;
    if (bid < 128) {
        int g = bid * 256 + tid;
        int s = g >> 2, i = g & 3;
        int kb = s >> 8, nb = (s >> 6) & 3, ln = s & 63;
        int c16 = ln & 15, hi = ln >> 4;
        int n = nb * 16 + c16;
        int k0 = kb * 32 + 8 * hi + 2 * i;
        unsigned int val = 0;
        if (n < CC) {
            const float* w1a = fc_W1 + (size_t)k0 * DD;
            const float* w1b = w1a + DD;
            float a0 = 0.f, a1 = 0.f;
            for (int d = 0; d < DD; ++d) {
                float w2 = fc_W2[d * CC + n];
                a0 = fmaf(w1a[d], w2, a0);
                a1 = fmaf(w1b[d], w2, a1);
            }
            val = rne_bf16(a0) | (rne_bf16(a1) << 16);
        }
        ((unsigned int*)(ws + OFF_WPACK))[g] = val;
    } else {
        if (tid < 64) {
            int c = tid;
            float acc = 0.f;
            if (c < 52) {
                acc = fc_b2[c];
                for (int d = 0; d < DD; ++d) acc = fmaf(fc_b1[d], fc_W2[d * CC + c], acc);
            }
            ws[OFF_BEFF + c] = acc;
        } else if (tid < 66) {
            ((unsigned*)(ws + OFF_RED))[tid - 64] = 0u;
        }
    }
}

// ================= K2: feats (0..255) || span (256..1279) || WAT (1280..1567) || tail (1568..1576) =================
__global__ __launch_bounds__(256) void k2_wide(
    const float* __restrict__ enc, const float* __restrict__ trans,
    const float* __restrict__ arg_W1, const float* __restrict__ arg_b1,
    const float* __restrict__ arg_W2, const float* __restrict__ arg_b2,
    const int* __restrict__ ts, const int* __restrict__ te,
    const int* __restrict__ es, const int* __restrict__ ee,
    float* __restrict__ ws)
{
    __shared__ f32x4 Ab[2][1024];   // 32KB
    __shared__ uint4v Bb[2][512];   // 16KB
    int bid = blockIdx.x, tid = threadIdx.x;
    int wid = tid >> 6, lane = tid & 63;

    if (bid >= 1568) {
        // -------- tail: EA / estart / estop / BA --------
        int f = (bid - 1568) * 256 + tid;  // [0, 2304)
        if (f < 2048) {
            int m = f >> 5, kp = f & 31;
            int k0 = 2 * kp;
            unsigned int wlo = 0, whi = 0;
            if (m < 52) {
                if (k0 < 52)     wlo = rne_bf16(expf(trans[k0 * CC + m]) * 0.015625f);
                if (k0 + 1 < 52) whi = rne_bf16(expf(trans[(k0 + 1) * CC + m]) * 0.015625f);
            }
            ((unsigned int*)(ws + OFF_EA))[f] = wlo | (whi << 16);
        } else if (f < 2112) {
            int j = f - 2048;
            ws[OFF_ESTART + j] = (j < 52) ? expf(trans[STARTT * CC + j]) : 0.f;
        } else if (f < 2176) {
            int j = f - 2112;
            ws[OFF_ESTOP + j] = (j < 52) ? expf(trans[j * CC + STOPP]) : 0.f;
        } else if (f < 2240) {
            int a = f - 2176;
            float acc = 0.f;
            if (a < 36) {
                acc = arg_b2[a];
                for (int d = 0; d < DD; ++d) acc = fmaf(arg_b1[d], arg_W2[d * AA + a], acc);
            }
            ws[OFF_BA + a] = acc;
        }
        return;
    }
    if (bid >= 1280) {
        // -------- WAT [h][a] --------
        int f = (bid - 1280) * 256 + tid;  // [0, 73728)
        int h = f / 36, a = f - h * 36;
        const float* w1 = arg_W1 + (size_t)h * DD;
        const float* w2 = arg_W2 + a;
        float a0 = 0.f, a1 = 0.f, a2 = 0.f, a3 = 0.f;
        for (int d = 0; d < DD; d += 4) {
            float4 w = *(const float4*)&w1[d];
            a0 = fmaf(w.x, w2[(size_t)(d + 0) * AA], a0);
            a1 = fmaf(w.y, w2[(size_t)(d + 1) * AA], a1);
            a2 = fmaf(w.z, w2[(size_t)(d + 2) * AA], a2);
            a3 = fmaf(w.w, w2[(size_t)(d + 3) * AA], a3);
        }
        ws[OFF_WAT + f] = (a0 + a1) + (a2 + a3);
        return;
    }
    if (bid >= 256) {
        // -------- span sums --------
        int sid = bid - 256;
        int b = sid >> 5, s = sid & 31;
        int st, en; float* outv;
        if (s < NTT) {
            st = ts[b * NTT + s]; en = te[b * NTT + s];
            outv = ws + OFF_TVEC + ((size_t)b * NTT + s) * HH;
        } else {
            int e = s - NTT;
            st = es[b * NEE + e]; en = ee[b * NEE + e];
            outv = ws + OFF_EVEC + ((size_t)b * NEE + e) * HH;
        }
        int h4 = tid * 4;
        float ax = 0, ay = 0, az = 0, aw = 0;
        for (int t = st; t < en; ++t) {
            float4 v = *(const float4*)&enc[((size_t)b * TT + t) * HH + h4];
            ax += v.x; ay += v.y; az += v.z; aw += v.w;
        }
        float inv = 1.f / (float)(en - st);
        float4 o; o.x = ax * inv; o.y = ay * inv; o.z = az * inv; o.w = aw * inv;
        *(float4*)&outv[h4] = o;
        return;
    }

    // -------- feats branch --------
    const uint4v* Wpack = (const uint4v*)(ws + OFF_WPACK);
    float* feats = ws + OFF_FEATS;
    float* ef64  = ws + OFF_EF64;
    int c16 = lane & 15, hi = lane >> 4;
    int c7 = c16 & 7;
    int row0 = bid * 64;
    int rowW = wid * 16 + c16;

    f32x4 acc[4];
#pragma unroll
    for (int nb = 0; nb < 4; ++nb) {
        float bv = ws[OFF_BEFF + nb * 16 + c16];
        acc[nb][0] = bv; acc[nb][1] = bv; acc[nb][2] = bv; acc[nb][3] = bv;
    }
    {
#pragma unroll
        for (int i = 0; i < 4; ++i) {
            int f = i * 256 + tid;
            int row = f >> 4, qp = f & 15;
            int q = (qp & 8) | ((qp & 7) ^ (row & 7));
            GLOAD16(enc + (size_t)(row0 + row) * HH + q * 4, &Ab[0][i * 256 + wid * 64]);
        }
#pragma unroll
        for (int i = 0; i < 2; ++i) {
            GLOAD16(Wpack + i * 256 + tid, &Bb[0][i * 256 + wid * 64]);
        }
    }
    for (int it = 0; it < 16; ++it) {
        __syncthreads();
        if (it < 15) {
            int buf = (it + 1) & 1;
            int k0 = (it + 1) * 64;
#pragma unroll
            for (int i = 0; i < 4; ++i) {
                int f = i * 256 + tid;
                int row = f >> 4, qp = f & 15;
                int q = (qp & 8) | ((qp & 7) ^ (row & 7));
                GLOAD16(enc + (size_t)(row0 + row) * HH + k0 + q * 4, &Ab[buf][i * 256 + wid * 64]);
            }
#pragma unroll
            for (int i = 0; i < 2; ++i) {
                GLOAD16(Wpack + (size_t)(it + 1) * 512 + i * 256 + tid, &Bb[buf][i * 256 + wid * 64]);
            }
        }
        int cb = it & 1;
#pragma unroll
        for (int kbL = 0; kbL < 2; ++kbL) {
            int q0 = (kbL * 8) | ((2 * hi) ^ c7);
            int q1 = q0 ^ 1;
            f32x4 a0 = Ab[cb][rowW * 16 + q0];
            f32x4 a1 = Ab[cb][rowW * 16 + q1];
            f32x4 lo = (c7 & 1) ? a1 : a0;
            f32x4 hf = (c7 & 1) ? a0 : a1;
            unsigned u0, u1, u2, u3;
            asm("v_cvt_pk_bf16_f32 %0, %1, %2" : "=v"(u0) : "v"(lo[0]), "v"(lo[1]));
            asm("v_cvt_pk_bf16_f32 %0, %1, %2" : "=v"(u1) : "v"(lo[2]), "v"(lo[3]));
            asm("v_cvt_pk_bf16_f32 %0, %1, %2" : "=v"(u2) : "v"(hf[0]), "v"(hf[1]));
            asm("v_cvt_pk_bf16_f32 %0, %1, %2" : "=v"(u3) : "v"(hf[2]), "v"(hf[3]));
            U4B A; A.u[0] = u0; A.u[1] = u1; A.u[2] = u2; A.u[3] = u3;
#pragma unroll
            for (int nb = 0; nb < 4; ++nb) {
                U4B Bf; Bf.u = Bb[cb][kbL * 256 + nb * 64 + lane];
                acc[nb] = __builtin_amdgcn_mfma_f32_16x16x32_bf16(A.b, Bf.b, acc[nb], 0, 0, 0);
            }
        }
    }
#pragma unroll
    for (int nb = 0; nb < 4; ++nb) {
        int col = nb * 16 + c16;
#pragma unroll
        for (int r = 0; r < 4; ++r) {
            size_t grow = row0 + wid * 16 + hi * 4 + r;
            float v = acc[nb][r];
            if (col < CC) {
                feats[grow * CC + col] = v;
                ef64[grow * 64 + col] = expf(v);
            } else {
                ef64[grow * 64 + col] = 0.f;
            }
        }
    }
}

// ================= K3: chunk (blocks 0..511, 4 waves) || arg head (blocks 512..767, 4 waves) =================
__global__ __launch_bounds__(256) void k3_chunk_arg(
    const int* __restrict__ lengths, float* __restrict__ ws)
{
    int bid = blockIdx.x, tid = threadIdx.x;
    int wid = tid >> 6, lane = tid & 63;

    if (bid >= 512) {
        // -------- arg branch --------
        int id = (bid - 512) * 4 + wid;
        int b = id >> 5, s = id & 31;
        int a = lane;
        const float* vec; const float* wt; float* outv; float base;
        if (s < NTT) {
            vec = ws + OFF_TVEC + ((size_t)b * NTT + s) * HH;
            wt  = ws + OFF_WAT + (size_t)1024 * AA;
            outv = ws + OFF_TLOG + ((size_t)b * NTT + s) * AA;
            base = (a < AA) ? ws[OFF_BA + a] : 0.f;
        } else {
            int e = s - NTT;
            vec = ws + OFF_EVEC + ((size_t)b * NEE + e) * HH;
            wt  = ws + OFF_WAT;
            outv = ws + OFF_ELOG + ((size_t)b * NEE + e) * AA;
            base = 0.f;
        }
        if (a < AA) {
            float a0 = 0, a1 = 0, a2 = 0, a3 = 0;
            for (int h = 0; h < HH; h += 4) {
                float4 vv = *(const float4*)&vec[h];
                a0 = fmaf(vv.x, wt[(size_t)(h + 0) * AA + a], a0);
                a1 = fmaf(vv.y, wt[(size_t)(h + 1) * AA + a], a1);
                a2 = fmaf(vv.z, wt[(size_t)(h + 2) * AA + a], a2);
                a3 = fmaf(vv.w, wt[(size_t)(h + 3) * AA + a], a3);
            }
            outv[a] = base + ((a0 + a1) + (a2 + a3));
        }
        return;
    }

    // -------- chunk branch: wave-unit cuid = bid*4+wid in [0,2048) --------
    int cuid = bid * 4 + wid;
    const unsigned short* EA = (const unsigned short*)(ws + OFF_EA);
    const float* ef64 = ws + OFF_EF64;
    unsigned int* Rout = (unsigned int*)(ws + OFF_RMAT);
    int b = cuid >> 6;
    int ch = (cuid >> 2) & (NCH - 1);
    int nb = cuid & 3;
    int c16 = lane & 15, hi = lane >> 4;
    int len = lengths[b];
    int t0 = 1 + ch * CL;
    int Le = len - t0; if (Le > CL) Le = CL;
    unsigned int* outm = Rout + (((size_t)b * NCH + ch) << 11);

    if (Le <= 0) {
#pragma unroll
        for (int q = 0; q < 8; ++q) {
            int col0 = nb * 16 + 2 * q;
            unsigned int val = 0;
            if (lane < 52) {
                if (col0 == lane)          val = 0x3F80u;
                else if (col0 + 1 == lane) val = 0x3F800000u;
            }
            outm[lane * 32 + nb * 8 + q] = val;
        }
        return;
    }

    bf16x8 Afr[4][2];
#pragma unroll
    for (int mb = 0; mb < 4; ++mb)
#pragma unroll
        for (int kb = 0; kb < 2; ++kb) {
            U4B x; x.u = *(const uint4v*)(EA + (size_t)(mb * 16 + c16) * 64 + kb * 32 + 8 * hi);
            Afr[mb][kb] = x.b;
        }

    unsigned int Bw[2][4];
#pragma unroll
    for (int kb = 0; kb < 2; ++kb)
#pragma unroll
        for (int j = 0; j < 4; ++j) {
            int col = nb * 16 + c16;
            int k0 = kb * 32 + 8 * hi + 2 * j;
            unsigned int v = 0;
            if (col < 52) {
                if (k0 == col)          v = 0x3F80u;
                else if (k0 + 1 == col) v = 0x3F800000u;
            }
            Bw[kb][j] = v;
        }

    unsigned int W[4][2];
    int hsel = hi >> 1;
    int src0 = c16 + 32 * (hi & 1);
    int src1 = src0 + 16;
    const float* efb = ef64 + (size_t)b * TT * 64;

    for (int s = 0; s < Le; ++s) {
        int t = t0 + s;
        U4B b0; b0.u = uint4v{Bw[0][0], Bw[0][1], Bw[0][2], Bw[0][3]};
        U4B b1; b1.u = uint4v{Bw[1][0], Bw[1][1], Bw[1][2], Bw[1][3]};
        f32x4 D[4];
#pragma unroll
        for (int mb = 0; mb < 4; ++mb) {
            f32x4 z = {0.f, 0.f, 0.f, 0.f};
            z = __builtin_amdgcn_mfma_f32_16x16x32_bf16(Afr[mb][0], b0.b, z, 0, 0, 0);
            z = __builtin_amdgcn_mfma_f32_16x16x32_bf16(Afr[mb][1], b1.b, z, 0, 0, 0);
            D[mb] = z;
        }
#pragma unroll
        for (int mb = 0; mb < 4; ++mb) {
            f32x4 cv = *(const f32x4*)(efb + (size_t)t * 64 + mb * 16 + 4 * hi);
            float d0 = D[mb][0] * cv[0];
            float d1 = D[mb][1] * cv[1];
            float d2 = D[mb][2] * cv[2];
            float d3 = D[mb][3] * cv[3];
            unsigned int w0, w1;
            asm("v_cvt_pk_bf16_f32 %0, %1, %2" : "=v"(w0) : "v"(d0), "v"(d1));
            asm("v_cvt_pk_bf16_f32 %0, %1, %2" : "=v"(w1) : "v"(d2), "v"(d3));
            W[mb][0] = w0; W[mb][1] = w1;
        }
#pragma unroll
        for (int kb = 0; kb < 2; ++kb)
#pragma unroll
            for (int j = 0; j < 4; ++j) {
                int src = (j < 2) ? src0 : src1;
                unsigned int va = (unsigned int)__shfl((int)W[2 * kb][j & 1], src, 64);
                unsigned int vb = (unsigned int)__shfl((int)W[2 * kb + 1][j & 1], src, 64);
                Bw[kb][j] = hsel ? vb : va;
            }
    }

#pragma unroll
    for (int mb = 0; mb < 4; ++mb)
#pragma unroll
        for (int w = 0; w < 2; ++w) {
            unsigned int my = W[mb][w];
            unsigned int ot = (unsigned int)__shfl_xor((int)my, 1, 64);
            unsigned int val;
            int r = 16 * mb + 4 * hi + 2 * w + (c16 & 1);
            if ((c16 & 1) == 0) val = (my & 0xFFFFu) | (ot << 16);
            else                val = (ot >> 16) | (my & 0xFFFF0000u);
            outm[r * 32 + nb * 8 + (c16 >> 1)] = val;
        }
}

// ================= K4: combine (blocks 0..31) || assemble (blocks 32..895) =================
__global__ __launch_bounds__(256) void k4_final(
    const float* __restrict__ trans,
    const int* __restrict__ tags, const int* __restrict__ lengths,
    const int* __restrict__ tmask, const int* __restrict__ emask,
    float* __restrict__ ws, float* __restrict__ out)
{
    __shared__ float vsh[64];
    int bid = blockIdx.x, tid = threadIdx.x;
    if (bid >= 32) {
        int idx = (bid - 32) * 256 + tid;
        int a = idx % AA;
        int p = idx / AA;
        int ne = p % NEE;
        int q = p / NEE;
        int nt = q & 7;
        int b = q >> 3;
        float m = (float)(tmask[b * NTT + nt] * emask[b * NEE + ne]);
        out[1 + idx] = (ws[OFF_TLOG + ((size_t)b * NTT + nt) * AA + a] +
                        ws[OFF_ELOG + ((size_t)b * NEE + ne) * AA + a]) * m;
        return;
    }
    if (tid >= 64) return;
    int b = bid, lane = tid;
    int len = lengths[b];
    const unsigned int* Rb = (const unsigned int*)(ws + OFF_RMAT) + ((size_t)b << 15);
    float v = 0.f;
    if (lane < 52) v = ws[OFF_ESTART + lane] * ws[OFF_EF64 + (size_t)b * TT * 64 + lane];
    int S = 0;

    uint4v bf0[8], bf1[8], bf2[8], bf3[8];

#define LOADM(BUF, IDX)                                                        \
    {                                                                          \
        const unsigned int* rr = Rb + (size_t)(IDX) * 2048 + (size_t)lane * 32;\
        _Pragma("unroll")                                                      \
        for (int q = 0; q < 8; ++q) BUF[q] = *(const uint4v*)(rr + q * 4);     \
    }

#define MATVEC(BUF)                                                            \
    {                                                                          \
        vsh[lane] = v;                                                         \
        float c0 = 0, c1 = 0, c2 = 0, c3 = 0;                                  \
        _Pragma("unroll")                                                      \
        for (int q = 0; q < 8; ++q) {                                          \
            uint4v u = BUF[q];                                                 \
            float4 va = *(const float4*)&vsh[q * 8];                           \
            float4 vb = *(const float4*)&vsh[q * 8 + 4];                       \
            c0 = fmaf(__uint_as_float(u[0] << 16), va.x, c0);                  \
            c0 = fmaf(__uint_as_float(u[0] & 0xFFFF0000u), va.y, c0);          \
            c1 = fmaf(__uint_as_float(u[1] << 16), va.z, c1);                  \
            c1 = fmaf(__uint_as_float(u[1] & 0xFFFF0000u), va.w, c1);          \
            c2 = fmaf(__uint_as_float(u[2] << 16), vb.x, c2);                  \
            c2 = fmaf(__uint_as_float(u[2] & 0xFFFF0000u), vb.y, c2);          \
            c3 = fmaf(__uint_as_float(u[3] << 16), vb.z, c3);                  \
            c3 = fmaf(__uint_as_float(u[3] & 0xFFFF0000u), vb.w, c3);          \
        }                                                                      \
        float acc = (c0 + c1) + (c2 + c3);                                     \
        float M = acc;                                                         \
        _Pragma("unroll")                                                      \
        for (int o = 32; o >= 1; o >>= 1) M = fmaxf(M, __shfl_xor(M, o, 64));  \
        int e = (int)((__float_as_uint(M) >> 23) & 0xFF) - 127;                \
        acc *= __uint_as_float((unsigned)(127 - e) << 23);                     \
        S += e; v = acc;                                                       \
    }

    // depth-4 rolling prefetch, fully unrolled (static buffer names)
    LOADM(bf0, 0) LOADM(bf1, 1) LOADM(bf2, 2) LOADM(bf3, 3)
    MATVEC(bf0)
    LOADM(bf0,  4) MATVEC(bf1)
    LOADM(bf1,  5) MATVEC(bf2)
    LOADM(bf2,  6) MATVEC(bf3)
    LOADM(bf3,  7) MATVEC(bf0)
    LOADM(bf0,  8) MATVEC(bf1)
    LOADM(bf1,  9) MATVEC(bf2)
    LOADM(bf2, 10) MATVEC(bf3)
    LOADM(bf3, 11) MATVEC(bf0)
    LOADM(bf0, 12) MATVEC(bf1)
    LOADM(bf1, 13) MATVEC(bf2)
    LOADM(bf2, 14) MATVEC(bf3)
    LOADM(bf3, 15) MATVEC(bf0)
    MATVEC(bf1)
    MATVEC(bf2)
    MATVEC(bf3)
#undef LOADM
#undef MATVEC

    float z = (lane < 52) ? v * ws[OFF_ESTOP + lane] : 0.f;
#pragma unroll
    for (int o = 32; o >= 1; o >>= 1) z += __shfl_xor(z, o, 64);
    float logZ = logf(z) + (float)(S + 6 * (len - 1)) * 0.6931471805599453f;

    const int* tg = tags + (size_t)b * TT;
    const float* fb = ws + OFF_FEATS + (size_t)b * TT * CC;
    float g = 0.f;
    for (int t = lane; t < TT; t += 64) {
        if (t < len) {
            int ct = tg[t];
            g += fb[(size_t)t * CC + ct];
            if (t + 1 < len) g += trans[ct * CC + tg[t + 1]];
        }
    }
#pragma unroll
    for (int o = 32; o >= 1; o >>= 1) g += __shfl_xor(g, o, 64);

    unsigned old = 0;
    if (lane == 0) {
        g += trans[STARTT * CC + tg[0]] + trans[tg[len - 1] * CC + STOPP];
        ws[OFF_LOSS + b] = logZ - g;
        __threadfence();
        unsigned* lcnt = (unsigned*)(ws + OFF_RED);
        old = __hip_atomic_fetch_add(lcnt, 1u, __ATOMIC_ACQ_REL, __HIP_MEMORY_SCOPE_AGENT);
    }
    old = (unsigned)__shfl((int)old, 0, 64);
    if (old == BB - 1) {
        __threadfence();
        float tv = (lane < BB) ? ((volatile float*)(ws + OFF_LOSS))[lane] : 0.f;
#pragma unroll
        for (int o = 32; o >= 1; o >>= 1) tv += __shfl_xor(tv, o, 64);
        if (lane == 0) out[0] = tv;
    }
}

extern "C" void kernel_launch(void* const* d_in, const int* in_sizes, int n_in,
                              void* d_out, int out_size, void* d_ws, size_t ws_size,
                              hipStream_t stream)
{
    const float* enc    = (const float*)d_in[0];
    const float* fc_W1  = (const float*)d_in[1];
    const float* fc_b1  = (const float*)d_in[2];
    const float* fc_W2  = (const float*)d_in[3];
    const float* fc_b2  = (const float*)d_in[4];
    const float* trans  = (const float*)d_in[5];
    const float* arg_W1 = (const float*)d_in[6];
    const float* arg_b1 = (const float*)d_in[7];
    const float* arg_W2 = (const float*)d_in[8];
    const float* arg_b2 = (const float*)d_in[9];
    const int* tags     = (const int*)d_in[10];
    const int* lengths  = (const int*)d_in[11];
    const int* tstarts  = (const int*)d_in[12];
    const int* tends    = (const int*)d_in[13];
    const int* tmask    = (const int*)d_in[14];
    const int* estarts  = (const int*)d_in[15];
    const int* eends    = (const int*)d_in[16];
    const int* emask    = (const int*)d_in[17];
    float* out = (float*)d_out;
    float* ws  = (float*)d_ws;

    hipLaunchKernelGGL(k1_pack, dim3(129), dim3(256), 0, stream,
                       fc_W1, fc_b1, fc_W2, fc_b2, ws);
    hipLaunchKernelGGL(k2_wide, dim3(1577), dim3(256), 0, stream,
                       enc, trans, arg_W1, arg_b1, arg_W2, arg_b2,
                       tstarts, tends, estarts, eends, ws);
    hipLaunchKernelGGL(k3_chunk_arg, dim3(768), dim3(256), 0, stream,
                       lengths, ws);
    hipLaunchKernelGGL(k4_final, dim3(896), dim3(256), 0, stream,
                       trans, tags, lengths, tmask, emask, ws, out);
}

// Round 12
// 100.877 us; speedup vs baseline: 1.0055x; 1.0055x over previous
//
#include <hip/hip_runtime.h>
#include <math.h>

#define BB 32
#define TT 512
#define HH 1024
#define DD 256
#define CC 52
#define NTT 8
#define NEE 24
#define AA 36
#define STARTT 50
#define STOPP 51
#define NCH 16     // chunks per batch
#define CL 32      // chunk length (steps)

// workspace float offsets
static const size_t OFF_WAT    = 0;        // 2048*36 = 73728, layout [h][a]
static const size_t OFF_BA     = 73728;    // 64
static const size_t OFF_ESTART = 73792;    // 64
static const size_t OFF_ESTOP  = 73856;    // 64
static const size_t OFF_BEFF   = 73920;    // 64
static const size_t OFF_EA     = 73984;    // 2048 u32 = 64x64 bf16 A-matrix (E64^T)
static const size_t OFF_WPACK  = 76032;    // 32768 u32 (128KB) MFMA-B layout W_eff
static const size_t OFF_FEATS  = 108800;   // 16384*52
static const size_t OFF_EF64   = 960768;   // 16384*64
static const size_t OFF_RMAT   = 2009344;  // 32*16*2048 u32 chunk matrices (4MB)
static const size_t OFF_TVEC   = 4106496;  // 32*8*1024
static const size_t OFF_EVEC   = 4368640;  // 32*24*1024
static const size_t OFF_TLOG   = 5155072;  // 32*8*36
static const size_t OFF_ELOG   = 5164288;  // 32*24*36
static const size_t OFF_LOSS   = 5191936;  // 32
static const size_t OFF_RED    = 5191968;  // u32[2]: [0]=loss counter

typedef __bf16 bf16x8 __attribute__((ext_vector_type(8)));
typedef float f32x4 __attribute__((ext_vector_type(4)));
typedef unsigned int uint4v __attribute__((ext_vector_type(4)));

union U4B { uint4v u; bf16x8 b; };

typedef const __attribute__((address_space(1))) void gvoid_t;
typedef __attribute__((address_space(3))) void lvoid_t;
#define GLOAD16(g, l) __builtin_amdgcn_global_load_lds((gvoid_t*)(g), (lvoid_t*)(l), 16, 0, 0)

static __device__ __forceinline__ unsigned int rne_bf16(float x) {
    unsigned int u = __float_as_uint(x);
    u += 0x7FFFu + ((u >> 16) & 1u);
    return u >> 16;
}

// ================= K1: WPACK + BEFF only (the true feats prerequisites) =================
__global__ __launch_bounds__(256) void k1_pack(
    const float* __restrict__ fc_W1, const float* __restrict__ fc_b1,
    const float* __restrict__ fc_W2, const float* __restrict__ fc_b2,
    float* __restrict__ ws)
{
    int bid = blockIdx.x, tid = threadIdx.x;
    if (bid < 128) {
        int g = bid * 256 + tid;
        int s = g >> 2, i = g & 3;
        int kb = s >> 8, nb = (s >> 6) & 3, ln = s & 63;
        int c16 = ln & 15, hi = ln >> 4;
        int n = nb * 16 + c16;
        int k0 = kb * 32 + 8 * hi + 2 * i;
        unsigned int val = 0;
        if (n < CC) {
            const float* w1a = fc_W1 + (size_t)k0 * DD;
            const float* w1b = w1a + DD;
            float a0 = 0.f, a1 = 0.f;
            for (int d = 0; d < DD; ++d) {
                float w2 = fc_W2[d * CC + n];
                a0 = fmaf(w1a[d], w2, a0);
                a1 = fmaf(w1b[d], w2, a1);
            }
            val = rne_bf16(a0) | (rne_bf16(a1) << 16);
        }
        ((unsigned int*)(ws + OFF_WPACK))[g] = val;
    } else {
        if (tid < 64) {
            int c = tid;
            float acc = 0.f;
            if (c < 52) {
                acc = fc_b2[c];
                for (int d = 0; d < DD; ++d) acc = fmaf(fc_b1[d], fc_W2[d * CC + c], acc);
            }
            ws[OFF_BEFF + c] = acc;
        } else if (tid < 66) {
            ((unsigned*)(ws + OFF_RED))[tid - 64] = 0u;
        }
    }
}

// ================= K2: feats 32-row tiles (0..511) || span (512..1535) || WAT (1536..1823) || tail (1824..1832) =================
__global__ __launch_bounds__(256) void k2_wide(
    const float* __restrict__ enc, const float* __restrict__ trans,
    const float* __restrict__ arg_W1, const float* __restrict__ arg_b1,
    const float* __restrict__ arg_W2, const float* __restrict__ arg_b2,
    const int* __restrict__ ts, const int* __restrict__ te,
    const int* __restrict__ es, const int* __restrict__ ee,
    float* __restrict__ ws)
{
    __shared__ f32x4 Ab[2][512];    // 32 rows x 16 quads, 8KB x2
    __shared__ uint4v Bb[2][512];   // 8KB x2
    int bid = blockIdx.x, tid = threadIdx.x;
    int wid = tid >> 6, lane = tid & 63;

    if (bid >= 1824) {
        // -------- tail: EA / estart / estop / BA --------
        int f = (bid - 1824) * 256 + tid;  // [0, 2304)
        if (f < 2048) {
            int m = f >> 5, kp = f & 31;
            int k0 = 2 * kp;
            unsigned int wlo = 0, whi = 0;
            if (m < 52) {
                if (k0 < 52)     wlo = rne_bf16(expf(trans[k0 * CC + m]) * 0.015625f);
                if (k0 + 1 < 52) whi = rne_bf16(expf(trans[(k0 + 1) * CC + m]) * 0.015625f);
            }
            ((unsigned int*)(ws + OFF_EA))[f] = wlo | (whi << 16);
        } else if (f < 2112) {
            int j = f - 2048;
            ws[OFF_ESTART + j] = (j < 52) ? expf(trans[STARTT * CC + j]) : 0.f;
        } else if (f < 2176) {
            int j = f - 2112;
            ws[OFF_ESTOP + j] = (j < 52) ? expf(trans[j * CC + STOPP]) : 0.f;
        } else if (f < 2240) {
            int a = f - 2176;
            float acc = 0.f;
            if (a < 36) {
                acc = arg_b2[a];
                for (int d = 0; d < DD; ++d) acc = fmaf(arg_b1[d], arg_W2[d * AA + a], acc);
            }
            ws[OFF_BA + a] = acc;
        }
        return;
    }
    if (bid >= 1536) {
        // -------- WAT [h][a] --------
        int f = (bid - 1536) * 256 + tid;  // [0, 73728)
        int h = f / 36, a = f - h * 36;
        const float* w1 = arg_W1 + (size_t)h * DD;
        const float* w2 = arg_W2 + a;
        float a0 = 0.f, a1 = 0.f, a2 = 0.f, a3 = 0.f;
        for (int d = 0; d < DD; d += 4) {
            float4 w = *(const float4*)&w1[d];
            a0 = fmaf(w.x, w2[(size_t)(d + 0) * AA], a0);
            a1 = fmaf(w.y, w2[(size_t)(d + 1) * AA], a1);
            a2 = fmaf(w.z, w2[(size_t)(d + 2) * AA], a2);
            a3 = fmaf(w.w, w2[(size_t)(d + 3) * AA], a3);
        }
        ws[OFF_WAT + f] = (a0 + a1) + (a2 + a3);
        return;
    }
    if (bid >= 512) {
        // -------- span sums --------
        int sid = bid - 512;
        int b = sid >> 5, s = sid & 31;
        int st, en; float* outv;
        if (s < NTT) {
            st = ts[b * NTT + s]; en = te[b * NTT + s];
            outv = ws + OFF_TVEC + ((size_t)b * NTT + s) * HH;
        } else {
            int e = s - NTT;
            st = es[b * NEE + e]; en = ee[b * NEE + e];
            outv = ws + OFF_EVEC + ((size_t)b * NEE + e) * HH;
        }
        int h4 = tid * 4;
        float ax = 0, ay = 0, az = 0, aw = 0;
        for (int t = st; t < en; ++t) {
            float4 v = *(const float4*)&enc[((size_t)b * TT + t) * HH + h4];
            ax += v.x; ay += v.y; az += v.z; aw += v.w;
        }
        float inv = 1.f / (float)(en - st);
        float4 o; o.x = ax * inv; o.y = ay * inv; o.z = az * inv; o.w = aw * inv;
        *(float4*)&outv[h4] = o;
        return;
    }

    // -------- feats branch: 32 rows per block, 2 blocks/CU --------
    const uint4v* Wpack = (const uint4v*)(ws + OFF_WPACK);
    float* feats = ws + OFF_FEATS;
    float* ef64  = ws + OFF_EF64;
    int c16 = lane & 15, hi = lane >> 4;
    int c7 = c16 & 7;
    int row0 = bid * 32;
    int rh = wid & 1;          // row half: rows rh*16 .. +15
    int np = wid >> 1;         // nb pair: nb = np*2, np*2+1
    int rowL = rh * 16 + c16;  // local row for A reads (row&7 == c7)

    f32x4 acc[2];
#pragma unroll
    for (int j = 0; j < 2; ++j) {
        float bv = ws[OFF_BEFF + (np * 2 + j) * 16 + c16];
        acc[j][0] = bv; acc[j][1] = bv; acc[j][2] = bv; acc[j][3] = bv;
    }
    {
#pragma unroll
        for (int i = 0; i < 2; ++i) {
            int f = i * 256 + tid;
            int row = f >> 4, qp = f & 15;
            int q = (qp & 8) | ((qp & 7) ^ (row & 7));
            GLOAD16(enc + (size_t)(row0 + row) * HH + q * 4, &Ab[0][i * 256 + wid * 64]);
        }
#pragma unroll
        for (int i = 0; i < 2; ++i) {
            GLOAD16(Wpack + i * 256 + tid, &Bb[0][i * 256 + wid * 64]);
        }
    }
    for (int it = 0; it < 16; ++it) {
        __syncthreads();
        if (it < 15) {
            int buf = (it + 1) & 1;
            int k0 = (it + 1) * 64;
#pragma unroll
            for (int i = 0; i < 2; ++i) {
                int f = i * 256 + tid;
                int row = f >> 4, qp = f & 15;
                int q = (qp & 8) | ((qp & 7) ^ (row & 7));
                GLOAD16(enc + (size_t)(row0 + row) * HH + k0 + q * 4, &Ab[buf][i * 256 + wid * 64]);
            }
#pragma unroll
            for (int i = 0; i < 2; ++i) {
                GLOAD16(Wpack + (size_t)(it + 1) * 512 + i * 256 + tid, &Bb[buf][i * 256 + wid * 64]);
            }
        }
        int cb = it & 1;
#pragma unroll
        for (int kbL = 0; kbL < 2; ++kbL) {
            int q0 = (kbL * 8) | ((2 * hi) ^ c7);
            int q1 = q0 ^ 1;
            f32x4 a0 = Ab[cb][rowL * 16 + q0];
            f32x4 a1 = Ab[cb][rowL * 16 + q1];
            f32x4 lo = (c7 & 1) ? a1 : a0;
            f32x4 hf = (c7 & 1) ? a0 : a1;
            unsigned u0, u1, u2, u3;
            asm("v_cvt_pk_bf16_f32 %0, %1, %2" : "=v"(u0) : "v"(lo[0]), "v"(lo[1]));
            asm("v_cvt_pk_bf16_f32 %0, %1, %2" : "=v"(u1) : "v"(lo[2]), "v"(lo[3]));
            asm("v_cvt_pk_bf16_f32 %0, %1, %2" : "=v"(u2) : "v"(hf[0]), "v"(hf[1]));
            asm("v_cvt_pk_bf16_f32 %0, %1, %2" : "=v"(u3) : "v"(hf[2]), "v"(hf[3]));
            U4B A; A.u[0] = u0; A.u[1] = u1; A.u[2] = u2; A.u[3] = u3;
#pragma unroll
            for (int j = 0; j < 2; ++j) {
                int nb = np * 2 + j;
                U4B Bf; Bf.u = Bb[cb][kbL * 256 + nb * 64 + lane];
                acc[j] = __builtin_amdgcn_mfma_f32_16x16x32_bf16(A.b, Bf.b, acc[j], 0, 0, 0);
            }
        }
    }
#pragma unroll
    for (int j = 0; j < 2; ++j) {
        int col = (np * 2 + j) * 16 + c16;
#pragma unroll
        for (int r = 0; r < 4; ++r) {
            size_t grow = row0 + rh * 16 + hi * 4 + r;
            float v = acc[j][r];
            if (col < CC) {
                feats[grow * CC + col] = v;
                ef64[grow * 64 + col] = expf(v);
            } else {
                ef64[grow * 64 + col] = 0.f;
            }
        }
    }
}

// ================= K3: chunk (blocks 0..511, 4 waves) || arg head (blocks 512..767, 4 waves) =================
__global__ __launch_bounds__(256) void k3_chunk_arg(
    const int* __restrict__ lengths, float* __restrict__ ws)
{
    int bid = blockIdx.x, tid = threadIdx.x;
    int wid = tid >> 6, lane = tid & 63;

    if (bid >= 512) {
        // -------- arg branch --------
        int id = (bid - 512) * 4 + wid;
        int b = id >> 5, s = id & 31;
        int a = lane;
        const float* vec; const float* wt; float* outv; float base;
        if (s < NTT) {
            vec = ws + OFF_TVEC + ((size_t)b * NTT + s) * HH;
            wt  = ws + OFF_WAT + (size_t)1024 * AA;
            outv = ws + OFF_TLOG + ((size_t)b * NTT + s) * AA;
            base = (a < AA) ? ws[OFF_BA + a] : 0.f;
        } else {
            int e = s - NTT;
            vec = ws + OFF_EVEC + ((size_t)b * NEE + e) * HH;
            wt  = ws + OFF_WAT;
            outv = ws + OFF_ELOG + ((size_t)b * NEE + e) * AA;
            base = 0.f;
        }
        if (a < AA) {
            float a0 = 0, a1 = 0, a2 = 0, a3 = 0;
            for (int h = 0; h < HH; h += 4) {
                float4 vv = *(const float4*)&vec[h];
                a0 = fmaf(vv.x, wt[(size_t)(h + 0) * AA + a], a0);
                a1 = fmaf(vv.y, wt[(size_t)(h + 1) * AA + a], a1);
                a2 = fmaf(vv.z, wt[(size_t)(h + 2) * AA + a], a2);
                a3 = fmaf(vv.w, wt[(size_t)(h + 3) * AA + a], a3);
            }
            outv[a] = base + ((a0 + a1) + (a2 + a3));
        }
        return;
    }

    // -------- chunk branch: wave-unit cuid = bid*4+wid in [0,2048) --------
    int cuid = bid * 4 + wid;
    const unsigned short* EA = (const unsigned short*)(ws + OFF_EA);
    const float* ef64 = ws + OFF_EF64;
    unsigned int* Rout = (unsigned int*)(ws + OFF_RMAT);
    int b = cuid >> 6;
    int ch = (cuid >> 2) & (NCH - 1);
    int nb = cuid & 3;
    int c16 = lane & 15, hi = lane >> 4;
    int len = lengths[b];
    int t0 = 1 + ch * CL;
    int Le = len - t0; if (Le > CL) Le = CL;
    unsigned int* outm = Rout + (((size_t)b * NCH + ch) << 11);

    if (Le <= 0) {
#pragma unroll
        for (int q = 0; q < 8; ++q) {
            int col0 = nb * 16 + 2 * q;
            unsigned int val = 0;
            if (lane < 52) {
                if (col0 == lane)          val = 0x3F80u;
                else if (col0 + 1 == lane) val = 0x3F800000u;
            }
            outm[lane * 32 + nb * 8 + q] = val;
        }
        return;
    }

    bf16x8 Afr[4][2];
#pragma unroll
    for (int mb = 0; mb < 4; ++mb)
#pragma unroll
        for (int kb = 0; kb < 2; ++kb) {
            U4B x; x.u = *(const uint4v*)(EA + (size_t)(mb * 16 + c16) * 64 + kb * 32 + 8 * hi);
            Afr[mb][kb] = x.b;
        }

    unsigned int Bw[2][4];
#pragma unroll
    for (int kb = 0; kb < 2; ++kb)
#pragma unroll
        for (int j = 0; j < 4; ++j) {
            int col = nb * 16 + c16;
            int k0 = kb * 32 + 8 * hi + 2 * j;
            unsigned int v = 0;
            if (col < 52) {
                if (k0 == col)          v = 0x3F80u;
                else if (k0 + 1 == col) v = 0x3F800000u;
            }
            Bw[kb][j] = v;
        }

    unsigned int W[4][2];
    int hsel = hi >> 1;
    int src0 = c16 + 32 * (hi & 1);
    int src1 = src0 + 16;
    const float* efb = ef64 + (size_t)b * TT * 64;

    for (int s = 0; s < Le; ++s) {
        int t = t0 + s;
        U4B b0; b0.u = uint4v{Bw[0][0], Bw[0][1], Bw[0][2], Bw[0][3]};
        U4B b1; b1.u = uint4v{Bw[1][0], Bw[1][1], Bw[1][2], Bw[1][3]};
        f32x4 D[4];
#pragma unroll
        for (int mb = 0; mb < 4; ++mb) {
            f32x4 z = {0.f, 0.f, 0.f, 0.f};
            z = __builtin_amdgcn_mfma_f32_16x16x32_bf16(Afr[mb][0], b0.b, z, 0, 0, 0);
            z = __builtin_amdgcn_mfma_f32_16x16x32_bf16(Afr[mb][1], b1.b, z, 0, 0, 0);
            D[mb] = z;
        }
#pragma unroll
        for (int mb = 0; mb < 4; ++mb) {
            f32x4 cv = *(const f32x4*)(efb + (size_t)t * 64 + mb * 16 + 4 * hi);
            float d0 = D[mb][0] * cv[0];
            float d1 = D[mb][1] * cv[1];
            float d2 = D[mb][2] * cv[2];
            float d3 = D[mb][3] * cv[3];
            unsigned int w0, w1;
            asm("v_cvt_pk_bf16_f32 %0, %1, %2" : "=v"(w0) : "v"(d0), "v"(d1));
            asm("v_cvt_pk_bf16_f32 %0, %1, %2" : "=v"(w1) : "v"(d2), "v"(d3));
            W[mb][0] = w0; W[mb][1] = w1;
        }
#pragma unroll
        for (int kb = 0; kb < 2; ++kb)
#pragma unroll
            for (int j = 0; j < 4; ++j) {
                int src = (j < 2) ? src0 : src1;
                unsigned int va = (unsigned int)__shfl((int)W[2 * kb][j & 1], src, 64);
                unsigned int vb = (unsigned int)__shfl((int)W[2 * kb + 1][j & 1], src, 64);
                Bw[kb][j] = hsel ? vb : va;
            }
    }

#pragma unroll
    for (int mb = 0; mb < 4; ++mb)
#pragma unroll
        for (int w = 0; w < 2; ++w) {
            unsigned int my = W[mb][w];
            unsigned int ot = (unsigned int)__shfl_xor((int)my, 1, 64);
            unsigned int val;
            int r = 16 * mb + 4 * hi + 2 * w + (c16 & 1);
            if ((c16 & 1) == 0) val = (my & 0xFFFFu) | (ot << 16);
            else                val = (ot >> 16) | (my & 0xFFFF0000u);
            outm[r * 32 + nb * 8 + (c16 >> 1)] = val;
        }
}

// ================= K4: combine (blocks 0..31) || assemble (blocks 32..895) =================
__global__ __launch_bounds__(256) void k4_final(
    const float* __restrict__ trans,
    const int* __restrict__ tags, const int* __restrict__ lengths,
    const int* __restrict__ tmask, const int* __restrict__ emask,
    float* __restrict__ ws, float* __restrict__ out)
{
    __shared__ float vsh[64];
    int bid = blockIdx.x, tid = threadIdx.x;
    if (bid >= 32) {
        int idx = (bid - 32) * 256 + tid;
        int a = idx % AA;
        int p = idx / AA;
        int ne = p % NEE;
        int q = p / NEE;
        int nt = q & 7;
        int b = q >> 3;
        float m = (float)(tmask[b * NTT + nt] * emask[b * NEE + ne]);
        out[1 + idx] = (ws[OFF_TLOG + ((size_t)b * NTT + nt) * AA + a] +
                        ws[OFF_ELOG + ((size_t)b * NEE + ne) * AA + a]) * m;
        return;
    }
    if (tid >= 64) return;
    int b = bid, lane = tid;
    int len = lengths[b];
    const unsigned int* Rb = (const unsigned int*)(ws + OFF_RMAT) + ((size_t)b << 15);
    float v = 0.f;
    if (lane < 52) v = ws[OFF_ESTART + lane] * ws[OFF_EF64 + (size_t)b * TT * 64 + lane];
    int S = 0;

    uint4v bf0[8], bf1[8], bf2[8], bf3[8];

#define LOADM(BUF, IDX)                                                        \
    {                                                                          \
        const unsigned int* rr = Rb + (size_t)(IDX) * 2048 + (size_t)lane * 32;\
        _Pragma("unroll")                                                      \
        for (int q = 0; q < 8; ++q) BUF[q] = *(const uint4v*)(rr + q * 4);     \
    }

#define MATVEC(BUF)                                                            \
    {                                                                          \
        vsh[lane] = v;                                                         \
        float c0 = 0, c1 = 0, c2 = 0, c3 = 0;                                  \
        _Pragma("unroll")                                                      \
        for (int q = 0; q < 8; ++q) {                                          \
            uint4v u = BUF[q];                                                 \
            float4 va = *(const float4*)&vsh[q * 8];                           \
            float4 vb = *(const float4*)&vsh[q * 8 + 4];                       \
            c0 = fmaf(__uint_as_float(u[0] << 16), va.x, c0);                  \
            c0 = fmaf(__uint_as_float(u[0] & 0xFFFF0000u), va.y, c0);          \
            c1 = fmaf(__uint_as_float(u[1] << 16), va.z, c1);                  \
            c1 = fmaf(__uint_as_float(u[1] & 0xFFFF0000u), va.w, c1);          \
            c2 = fmaf(__uint_as_float(u[2] << 16), vb.x, c2);                  \
            c2 = fmaf(__uint_as_float(u[2] & 0xFFFF0000u), vb.y, c2);          \
            c3 = fmaf(__uint_as_float(u[3] << 16), vb.z, c3);                  \
            c3 = fmaf(__uint_as_float(u[3] & 0xFFFF0000u), vb.w, c3);          \
        }                                                                      \
        float acc = (c0 + c1) + (c2 + c3);                                     \
        float M = acc;                                                         \
        _Pragma("unroll")                                                      \
        for (int o = 32; o >= 1; o >>= 1) M = fmaxf(M, __shfl_xor(M, o, 64));  \
        int e = (int)((__float_as_uint(M) >> 23) & 0xFF) - 127;                \
        acc *= __uint_as_float((unsigned)(127 - e) << 23);                     \
        S += e; v = acc;                                                       \
    }

    // depth-4 rolling prefetch, fully unrolled (static buffer names)
    LOADM(bf0, 0) LOADM(bf1, 1) LOADM(bf2, 2) LOADM(bf3, 3)
    MATVEC(bf0)
    LOADM(bf0,  4) MATVEC(bf1)
    LOADM(bf1,  5) MATVEC(bf2)
    LOADM(bf2,  6) MATVEC(bf3)
    LOADM(bf3,  7) MATVEC(bf0)
    LOADM(bf0,  8) MATVEC(bf1)
    LOADM(bf1,  9) MATVEC(bf2)
    LOADM(bf2, 10) MATVEC(bf3)
    LOADM(bf3, 11) MATVEC(bf0)
    LOADM(bf0, 12) MATVEC(bf1)
    LOADM(bf1, 13) MATVEC(bf2)
    LOADM(bf2, 14) MATVEC(bf3)
    LOADM(bf3, 15) MATVEC(bf0)
    MATVEC(bf1)
    MATVEC(bf2)
    MATVEC(bf3)
#undef LOADM
#undef MATVEC

    float z = (lane < 52) ? v * ws[OFF_ESTOP + lane] : 0.f;
#pragma unroll
    for (int o = 32; o >= 1; o >>= 1) z += __shfl_xor(z, o, 64);
    float logZ = logf(z) + (float)(S + 6 * (len - 1)) * 0.6931471805599453f;

    const int* tg = tags + (size_t)b * TT;
    const float* fb = ws + OFF_FEATS + (size_t)b * TT * CC;
    float g = 0.f;
    for (int t = lane; t < TT; t += 64) {
        if (t < len) {
            int ct = tg[t];
            g += fb[(size_t)t * CC + ct];
            if (t + 1 < len) g += trans[ct * CC + tg[t + 1]];
        }
    }
#pragma unroll
    for (int o = 32; o >= 1; o >>= 1) g += __shfl_xor(g, o, 64);

    unsigned old = 0;
    if (lane == 0) {
        g += trans[STARTT * CC + tg[0]] + trans[tg[len - 1] * CC + STOPP];
        ws[OFF_LOSS + b] = logZ - g;
        __threadfence();
        unsigned* lcnt = (unsigned*)(ws + OFF_RED);
        old = __hip_atomic_fetch_add(lcnt, 1u, __ATOMIC_ACQ_REL, __HIP_MEMORY_SCOPE_AGENT);
    }
    old = (unsigned)__shfl((int)old, 0, 64);
    if (old == BB - 1) {
        __threadfence();
        float tv = (lane < BB) ? ((volatile float*)(ws + OFF_LOSS))[lane] : 0.f;
#pragma unroll
        for (int o = 32; o >= 1; o >>= 1) tv += __shfl_xor(tv, o, 64);
        if (lane == 0) out[0] = tv;
    }
}

extern "C" void kernel_launch(void* const* d_in, const int* in_sizes, int n_in,
                              void* d_out, int out_size, void* d_ws, size_t ws_size,
                              hipStream_t stream)
{
    const float* enc    = (const float*)d_in[0];
    const float* fc_W1  = (const float*)d_in[1];
    const float* fc_b1  = (const float*)d_in[2];
    const float* fc_W2  = (const float*)d_in[3];
    const float* fc_b2  = (const float*)d_in[4];
    const float* trans  = (const float*)d_in[5];
    const float* arg_W1 = (const float*)d_in[6];
    const float* arg_b1 = (const float*)d_in[7];
    const float* arg_W2 = (const float*)d_in[8];
    const float* arg_b2 = (const float*)d_in[9];
    const int* tags     = (const int*)d_in[10];
    const int* lengths  = (const int*)d_in[11];
    const int* tstarts  = (const int*)d_in[12];
    const int* tends    = (const int*)d_in[13];
    const int* tmask    = (const int*)d_in[14];
    const int* estarts  = (const int*)d_in[15];
    const int* eends    = (const int*)d_in[16];
    const int* emask    = (const int*)d_in[17];
    float* out = (float*)d_out;
    float* ws  = (float*)d_ws;

    hipLaunchKernelGGL(k1_pack, dim3(129), dim3(256), 0, stream,
                       fc_W1, fc_b1, fc_W2, fc_b2, ws);
    hipLaunchKernelGGL(k2_wide, dim3(1833), dim3(256), 0, stream,
                       enc, trans, arg_W1, arg_b1, arg_W2, arg_b2,
                       tstarts, tends, estarts, eends, ws);
    hipLaunchKernelGGL(k3_chunk_arg, dim3(768), dim3(256), 0, stream,
                       lengths, ws);
    hipLaunchKernelGGL(k4_final, dim3(896), dim3(256), 0, stream,
                       trans, tags, lengths, tmask, emask, ws, out);
}

// Round 13
// 84.404 us; speedup vs baseline: 1.2018x; 1.1952x over previous
//
#include <hip/hip_runtime.h>
#include <math.h>

#define BB 32
#define TT 512
#define HH 1024
#define DD 256
#define CC 52
#define NTT 8
#define NEE 24
#define AA 36
#define STARTT 50
#define STOPP 51
#define NCH 16     // chunks per batch
#define CL 32      // chunk length (steps)

// workspace float offsets
static const size_t OFF_WAT    = 0;        // 2048*36 = 73728, layout [h][a]
static const size_t OFF_BA     = 73728;    // 64
static const size_t OFF_ESTART = 73792;    // 64
static const size_t OFF_ESTOP  = 73856;    // 64
static const size_t OFF_BEFF   = 73920;    // 64
static const size_t OFF_EA     = 73984;    // 2048 u32 = 64x64 bf16 A-matrix (E64^T)
static const size_t OFF_WPACK  = 76032;    // 32768 u32 (128KB) MFMA-B layout W_eff
static const size_t OFF_FEATS  = 108800;   // 16384*52
static const size_t OFF_RMAT   = 2009344;  // 32*16*2048 u32 chunk matrices (4MB)
static const size_t OFF_TVEC   = 4106496;  // 32*8*1024
static const size_t OFF_EVEC   = 4368640;  // 32*24*1024
static const size_t OFF_TLOG   = 5155072;  // 32*8*36
static const size_t OFF_ELOG   = 5164288;  // 32*24*36
static const size_t OFF_LOSS   = 5191936;  // 32
static const size_t OFF_RED    = 5191968;  // u32[2]: [0]=loss counter

typedef __bf16 bf16x8 __attribute__((ext_vector_type(8)));
typedef float f32x4 __attribute__((ext_vector_type(4)));
typedef unsigned int uint4v __attribute__((ext_vector_type(4)));

union U4B { uint4v u; bf16x8 b; };

typedef const __attribute__((address_space(1))) void gvoid_t;
typedef __attribute__((address_space(3))) void lvoid_t;
#define GLOAD16(g, l) __builtin_amdgcn_global_load_lds((gvoid_t*)(g), (lvoid_t*)(l), 16, 0, 0)

static __device__ __forceinline__ unsigned int rne_bf16(float x) {
    unsigned int u = __float_as_uint(x);
    u += 0x7FFFu + ((u >> 16) & 1u);
    return u >> 16;
}

// ================= K1: weight prep + span sums (round-9 proven layout) =================
__global__ __launch_bounds__(256) void k1_prep_span(
    const float* __restrict__ enc,
    const float* __restrict__ fc_W1, const float* __restrict__ fc_b1,
    const float* __restrict__ fc_W2, const float* __restrict__ fc_b2,
    const float* __restrict__ trans,
    const float* __restrict__ arg_W1, const float* __restrict__ arg_b1,
    const float* __restrict__ arg_W2, const float* __restrict__ arg_b2,
    const int* __restrict__ ts, const int* __restrict__ te,
    const int* __restrict__ es, const int* __restrict__ ee,
    float* __restrict__ ws)
{
    int bid = blockIdx.x, tid = threadIdx.x;
    if (bid < 128) {
        int g = bid * 256 + tid;
        int s = g >> 2, i = g & 3;
        int kb = s >> 8, nb = (s >> 6) & 3, ln = s & 63;
        int c16 = ln & 15, hi = ln >> 4;
        int n = nb * 16 + c16;
        int k0 = kb * 32 + 8 * hi + 2 * i;
        unsigned int val = 0;
        if (n < CC) {
            const float* w1a = fc_W1 + (size_t)k0 * DD;
            const float* w1b = w1a + DD;
            float a0 = 0.f, a1 = 0.f;
            for (int d = 0; d < DD; ++d) {
                float w2 = fc_W2[d * CC + n];
                a0 = fmaf(w1a[d], w2, a0);
                a1 = fmaf(w1b[d], w2, a1);
            }
            val = rne_bf16(a0) | (rne_bf16(a1) << 16);
        }
        ((unsigned int*)(ws + OFF_WPACK))[g] = val;
    } else if (bid < 416) {
        int f = (bid - 128) * 256 + tid;
        int h = f / 36, a = f - h * 36;
        const float* w1 = arg_W1 + (size_t)h * DD;
        const float* w2 = arg_W2 + a;
        float a0 = 0.f, a1 = 0.f, a2 = 0.f, a3 = 0.f;
        for (int d = 0; d < DD; d += 4) {
            float4 w = *(const float4*)&w1[d];
            a0 = fmaf(w.x, w2[(size_t)(d + 0) * AA], a0);
            a1 = fmaf(w.y, w2[(size_t)(d + 1) * AA], a1);
            a2 = fmaf(w.z, w2[(size_t)(d + 2) * AA], a2);
            a3 = fmaf(w.w, w2[(size_t)(d + 3) * AA], a3);
        }
        ws[OFF_WAT + f] = (a0 + a1) + (a2 + a3);
    } else if (bid < 1440) {
        int sid = bid - 416;
        int b = sid >> 5, s = sid & 31;
        int st, en; float* outv;
        if (s < NTT) {
            st = ts[b * NTT + s]; en = te[b * NTT + s];
            outv = ws + OFF_TVEC + ((size_t)b * NTT + s) * HH;
        } else {
            int e = s - NTT;
            st = es[b * NEE + e]; en = ee[b * NEE + e];
            outv = ws + OFF_EVEC + ((size_t)b * NEE + e) * HH;
        }
        int h4 = tid * 4;
        float ax = 0, ay = 0, az = 0, aw = 0;
        for (int t = st; t < en; ++t) {
            float4 v = *(const float4*)&enc[((size_t)b * TT + t) * HH + h4];
            ax += v.x; ay += v.y; az += v.z; aw += v.w;
        }
        float inv = 1.f / (float)(en - st);
        float4 o; o.x = ax * inv; o.y = ay * inv; o.z = az * inv; o.w = aw * inv;
        *(float4*)&outv[h4] = o;
    } else {
        int f = (bid - 1440) * 256 + tid;  // [0, 2560)
        if (f < 2048) {
            int m = f >> 5, kp = f & 31;
            int k0 = 2 * kp;
            unsigned int wlo = 0, whi = 0;
            if (m < 52) {
                if (k0 < 52)     wlo = rne_bf16(expf(trans[k0 * CC + m]) * 0.015625f);
                if (k0 + 1 < 52) whi = rne_bf16(expf(trans[(k0 + 1) * CC + m]) * 0.015625f);
            }
            ((unsigned int*)(ws + OFF_EA))[f] = wlo | (whi << 16);
        } else if (f < 2112) {
            int j = f - 2048;
            ws[OFF_ESTART + j] = (j < 52) ? expf(trans[STARTT * CC + j]) : 0.f;
        } else if (f < 2176) {
            int j = f - 2112;
            ws[OFF_ESTOP + j] = (j < 52) ? expf(trans[j * CC + STOPP]) : 0.f;
        } else if (f < 2240) {
            int c = f - 2176;
            float acc = 0.f;
            if (c < 52) {
                acc = fc_b2[c];
                for (int d = 0; d < DD; ++d) acc = fmaf(fc_b1[d], fc_W2[d * CC + c], acc);
            }
            ws[OFF_BEFF + c] = acc;
        } else if (f < 2304) {
            int a = f - 2240;
            float acc = 0.f;
            if (a < 36) {
                acc = arg_b2[a];
                for (int d = 0; d < DD; ++d) acc = fmaf(arg_b1[d], arg_W2[d * AA + a], acc);
            }
            ws[OFF_BA + a] = acc;
        } else if (f < 2306) {
            ((unsigned*)(ws + OFF_RED))[f - 2304] = 0u;
        }
    }
}

// ================= K2: fused feats+chunk (blocks 0..511, block = (b,ch)) || arg (512..767) =================
__global__ __launch_bounds__(256) void k2_fused(
    const float* __restrict__ enc, const int* __restrict__ lengths,
    float* __restrict__ ws)
{
    __shared__ f32x4 Ab[2][512];    // 16KB
    __shared__ uint4v Bb[2][512];   // 16KB
    __shared__ float efsh[32][64];  // 8KB
    int bid = blockIdx.x, tid = threadIdx.x;
    int wid = tid >> 6, lane = tid & 63;
    int c16 = lane & 15, hi = lane >> 4;

    if (bid >= 512) {
        // -------- arg branch --------
        int id = (bid - 512) * 4 + wid;
        int b = id >> 5, s = id & 31;
        int a = lane;
        const float* vec; const float* wt; float* outv; float base;
        if (s < NTT) {
            vec = ws + OFF_TVEC + ((size_t)b * NTT + s) * HH;
            wt  = ws + OFF_WAT + (size_t)1024 * AA;
            outv = ws + OFF_TLOG + ((size_t)b * NTT + s) * AA;
            base = (a < AA) ? ws[OFF_BA + a] : 0.f;
        } else {
            int e = s - NTT;
            vec = ws + OFF_EVEC + ((size_t)b * NEE + e) * HH;
            wt  = ws + OFF_WAT;
            outv = ws + OFF_ELOG + ((size_t)b * NEE + e) * AA;
            base = 0.f;
        }
        if (a < AA) {
            float a0 = 0, a1 = 0, a2 = 0, a3 = 0;
            for (int h = 0; h < HH; h += 4) {
                float4 vv = *(const float4*)&vec[h];
                a0 = fmaf(vv.x, wt[(size_t)(h + 0) * AA + a], a0);
                a1 = fmaf(vv.y, wt[(size_t)(h + 1) * AA + a], a1);
                a2 = fmaf(vv.z, wt[(size_t)(h + 2) * AA + a], a2);
                a3 = fmaf(vv.w, wt[(size_t)(h + 3) * AA + a], a3);
            }
            outv[a] = base + ((a0 + a1) + (a2 + a3));
        }
        return;
    }

    // -------- feats phase: 32 rows (batch b = bid>>4, chunk ch = bid&15) --------
    const uint4v* Wpack = (const uint4v*)(ws + OFF_WPACK);
    float* feats = ws + OFF_FEATS;
    int c7 = c16 & 7;
    int row0 = bid * 32;
    int rh = wid & 1;
    int np = wid >> 1;
    int rowL = rh * 16 + c16;

    f32x4 acc[2];
#pragma unroll
    for (int j = 0; j < 2; ++j) {
        float bv = ws[OFF_BEFF + (np * 2 + j) * 16 + c16];
        acc[j][0] = bv; acc[j][1] = bv; acc[j][2] = bv; acc[j][3] = bv;
    }
    {
#pragma unroll
        for (int i = 0; i < 2; ++i) {
            int f = i * 256 + tid;
            int row = f >> 4, qp = f & 15;
            int q = (qp & 8) | ((qp & 7) ^ (row & 7));
            GLOAD16(enc + (size_t)(row0 + row) * HH + q * 4, &Ab[0][i * 256 + wid * 64]);
        }
#pragma unroll
        for (int i = 0; i < 2; ++i) {
            GLOAD16(Wpack + i * 256 + tid, &Bb[0][i * 256 + wid * 64]);
        }
    }
    for (int it = 0; it < 16; ++it) {
        __syncthreads();
        if (it < 15) {
            int buf = (it + 1) & 1;
            int k0 = (it + 1) * 64;
#pragma unroll
            for (int i = 0; i < 2; ++i) {
                int f = i * 256 + tid;
                int row = f >> 4, qp = f & 15;
                int q = (qp & 8) | ((qp & 7) ^ (row & 7));
                GLOAD16(enc + (size_t)(row0 + row) * HH + k0 + q * 4, &Ab[buf][i * 256 + wid * 64]);
            }
#pragma unroll
            for (int i = 0; i < 2; ++i) {
                GLOAD16(Wpack + (size_t)(it + 1) * 512 + i * 256 + tid, &Bb[buf][i * 256 + wid * 64]);
            }
        }
        int cb = it & 1;
#pragma unroll
        for (int kbL = 0; kbL < 2; ++kbL) {
            int q0 = (kbL * 8) | ((2 * hi) ^ c7);
            int q1 = q0 ^ 1;
            f32x4 a0 = Ab[cb][rowL * 16 + q0];
            f32x4 a1 = Ab[cb][rowL * 16 + q1];
            f32x4 lo = (c7 & 1) ? a1 : a0;
            f32x4 hf = (c7 & 1) ? a0 : a1;
            unsigned u0, u1, u2, u3;
            asm("v_cvt_pk_bf16_f32 %0, %1, %2" : "=v"(u0) : "v"(lo[0]), "v"(lo[1]));
            asm("v_cvt_pk_bf16_f32 %0, %1, %2" : "=v"(u1) : "v"(lo[2]), "v"(lo[3]));
            asm("v_cvt_pk_bf16_f32 %0, %1, %2" : "=v"(u2) : "v"(hf[0]), "v"(hf[1]));
            asm("v_cvt_pk_bf16_f32 %0, %1, %2" : "=v"(u3) : "v"(hf[2]), "v"(hf[3]));
            U4B A; A.u[0] = u0; A.u[1] = u1; A.u[2] = u2; A.u[3] = u3;
#pragma unroll
            for (int j = 0; j < 2; ++j) {
                int nb = np * 2 + j;
                U4B Bf; Bf.u = Bb[cb][kbL * 256 + nb * 64 + lane];
                acc[j] = __builtin_amdgcn_mfma_f32_16x16x32_bf16(A.b, Bf.b, acc[j], 0, 0, 0);
            }
        }
    }
    // epilogue: feats -> global; exp(feats) -> LDS efsh
#pragma unroll
    for (int j = 0; j < 2; ++j) {
        int col = (np * 2 + j) * 16 + c16;
#pragma unroll
        for (int r = 0; r < 4; ++r) {
            int lrow = rh * 16 + hi * 4 + r;
            float v = acc[j][r];
            float ev = 0.f;
            if (col < CC) {
                feats[(size_t)(row0 + lrow) * CC + col] = v;
                ev = expf(v);
            }
            efsh[lrow][col] = ev;
        }
    }
    __syncthreads();

    // -------- chunk phase: wave wid owns column block nb=wid --------
    int b = bid >> 4, ch = bid & 15;
    int len = lengths[b];
    int tstart = ch * CL + (ch == 0 ? 1 : 0);
    int tend = ch * CL + CL; if (tend > len) tend = len;
    int Le = tend - tstart;
    int nb = wid;
    unsigned int* outm = (unsigned int*)(ws + OFF_RMAT) + (((size_t)b * NCH + ch) << 11);

    if (Le <= 0) {
#pragma unroll
        for (int q = 0; q < 8; ++q) {
            int col0 = nb * 16 + 2 * q;
            unsigned int val = 0;
            if (lane < 52) {
                if (col0 == lane)          val = 0x3F80u;
                else if (col0 + 1 == lane) val = 0x3F800000u;
            }
            outm[lane * 32 + nb * 8 + q] = val;
        }
        return;
    }

    const unsigned short* EA = (const unsigned short*)(ws + OFF_EA);
    bf16x8 Afr[4][2];
#pragma unroll
    for (int mb = 0; mb < 4; ++mb)
#pragma unroll
        for (int kb = 0; kb < 2; ++kb) {
            U4B x; x.u = *(const uint4v*)(EA + (size_t)(mb * 16 + c16) * 64 + kb * 32 + 8 * hi);
            Afr[mb][kb] = x.b;
        }

    unsigned int Bw[2][4];
#pragma unroll
    for (int kb = 0; kb < 2; ++kb)
#pragma unroll
        for (int j = 0; j < 4; ++j) {
            int col = nb * 16 + c16;
            int k0 = kb * 32 + 8 * hi + 2 * j;
            unsigned int v = 0;
            if (col < 52) {
                if (k0 == col)          v = 0x3F80u;
                else if (k0 + 1 == col) v = 0x3F800000u;
            }
            Bw[kb][j] = v;
        }

    unsigned int W[4][2];
    int hsel = hi >> 1;
    int src0 = c16 + 32 * (hi & 1);
    int src1 = src0 + 16;
    int rbase = tstart - ch * CL;   // 1 for ch==0, else 0

    for (int s = 0; s < Le; ++s) {
        int r = rbase + s;
        U4B b0; b0.u = uint4v{Bw[0][0], Bw[0][1], Bw[0][2], Bw[0][3]};
        U4B b1; b1.u = uint4v{Bw[1][0], Bw[1][1], Bw[1][2], Bw[1][3]};
        f32x4 D[4];
#pragma unroll
        for (int mb = 0; mb < 4; ++mb) {
            f32x4 z = {0.f, 0.f, 0.f, 0.f};
            z = __builtin_amdgcn_mfma_f32_16x16x32_bf16(Afr[mb][0], b0.b, z, 0, 0, 0);
            z = __builtin_amdgcn_mfma_f32_16x16x32_bf16(Afr[mb][1], b1.b, z, 0, 0, 0);
            D[mb] = z;
        }
#pragma unroll
        for (int mb = 0; mb < 4; ++mb) {
            f32x4 cv = *(const f32x4*)&efsh[r][mb * 16 + 4 * hi];
            float d0 = D[mb][0] * cv[0];
            float d1 = D[mb][1] * cv[1];
            float d2 = D[mb][2] * cv[2];
            float d3 = D[mb][3] * cv[3];
            unsigned int w0, w1;
            asm("v_cvt_pk_bf16_f32 %0, %1, %2" : "=v"(w0) : "v"(d0), "v"(d1));
            asm("v_cvt_pk_bf16_f32 %0, %1, %2" : "=v"(w1) : "v"(d2), "v"(d3));
            W[mb][0] = w0; W[mb][1] = w1;
        }
#pragma unroll
        for (int kb = 0; kb < 2; ++kb)
#pragma unroll
            for (int j = 0; j < 4; ++j) {
                int src = (j < 2) ? src0 : src1;
                unsigned int va = (unsigned int)__shfl((int)W[2 * kb][j & 1], src, 64);
                unsigned int vb = (unsigned int)__shfl((int)W[2 * kb + 1][j & 1], src, 64);
                Bw[kb][j] = hsel ? vb : va;
            }
    }

#pragma unroll
    for (int mb = 0; mb < 4; ++mb)
#pragma unroll
        for (int w = 0; w < 2; ++w) {
            unsigned int my = W[mb][w];
            unsigned int ot = (unsigned int)__shfl_xor((int)my, 1, 64);
            unsigned int val;
            int r = 16 * mb + 4 * hi + 2 * w + (c16 & 1);
            if ((c16 & 1) == 0) val = (my & 0xFFFFu) | (ot << 16);
            else                val = (ot >> 16) | (my & 0xFFFF0000u);
            outm[r * 32 + nb * 8 + (c16 >> 1)] = val;
        }
}

// ================= K3: combine (blocks 0..31) || assemble (blocks 32..895) =================
__global__ __launch_bounds__(256) void k3_final(
    const float* __restrict__ trans,
    const int* __restrict__ tags, const int* __restrict__ lengths,
    const int* __restrict__ tmask, const int* __restrict__ emask,
    float* __restrict__ ws, float* __restrict__ out)
{
    __shared__ float vsh[64];
    int bid = blockIdx.x, tid = threadIdx.x;
    if (bid >= 32) {
        int idx = (bid - 32) * 256 + tid;
        int a = idx % AA;
        int p = idx / AA;
        int ne = p % NEE;
        int q = p / NEE;
        int nt = q & 7;
        int b = q >> 3;
        float m = (float)(tmask[b * NTT + nt] * emask[b * NEE + ne]);
        out[1 + idx] = (ws[OFF_TLOG + ((size_t)b * NTT + nt) * AA + a] +
                        ws[OFF_ELOG + ((size_t)b * NEE + ne) * AA + a]) * m;
        return;
    }
    if (tid >= 64) return;
    int b = bid, lane = tid;
    int len = lengths[b];
    const unsigned int* Rb = (const unsigned int*)(ws + OFF_RMAT) + ((size_t)b << 15);
    float v = 0.f;
    if (lane < 52) v = ws[OFF_ESTART + lane] * expf(ws[OFF_FEATS + (size_t)b * TT * CC + lane]);
    int S = 0;

    uint4v bf0[8], bf1[8], bf2[8], bf3[8];

#define LOADM(BUF, IDX)                                                        \
    {                                                                          \
        const unsigned int* rr = Rb + (size_t)(IDX) * 2048 + (size_t)lane * 32;\
        _Pragma("unroll")                                                      \
        for (int q = 0; q < 8; ++q) BUF[q] = *(const uint4v*)(rr + q * 4);     \
    }

#define MATVEC(BUF)                                                            \
    {                                                                          \
        vsh[lane] = v;                                                         \
        float c0 = 0, c1 = 0, c2 = 0, c3 = 0;                                  \
        _Pragma("unroll")                                                      \
        for (int q = 0; q < 8; ++q) {                                          \
            uint4v u = BUF[q];                                                 \
            float4 va = *(const float4*)&vsh[q * 8];                           \
            float4 vb = *(const float4*)&vsh[q * 8 + 4];                       \
            c0 = fmaf(__uint_as_float(u[0] << 16), va.x, c0);                  \
            c0 = fmaf(__uint_as_float(u[0] & 0xFFFF0000u), va.y, c0);          \
            c1 = fmaf(__uint_as_float(u[1] << 16), va.z, c1);                  \
            c1 = fmaf(__uint_as_float(u[1] & 0xFFFF0000u), va.w, c1);          \
            c2 = fmaf(__uint_as_float(u[2] << 16), vb.x, c2);                  \
            c2 = fmaf(__uint_as_float(u[2] & 0xFFFF0000u), vb.y, c2);          \
            c3 = fmaf(__uint_as_float(u[3] << 16), vb.z, c3);                  \
            c3 = fmaf(__uint_as_float(u[3] & 0xFFFF0000u), vb.w, c3);          \
        }                                                                      \
        float acc = (c0 + c1) + (c2 + c3);                                     \
        float M = acc;                                                         \
        _Pragma("unroll")                                                      \
        for (int o = 32; o >= 1; o >>= 1) M = fmaxf(M, __shfl_xor(M, o, 64));  \
        int e = (int)((__float_as_uint(M) >> 23) & 0xFF) - 127;                \
        acc *= __uint_as_float((unsigned)(127 - e) << 23);                     \
        S += e; v = acc;                                                       \
    }

    LOADM(bf0, 0) LOADM(bf1, 1) LOADM(bf2, 2) LOADM(bf3, 3)
    MATVEC(bf0)
    LOADM(bf0,  4) MATVEC(bf1)
    LOADM(bf1,  5) MATVEC(bf2)
    LOADM(bf2,  6) MATVEC(bf3)
    LOADM(bf3,  7) MATVEC(bf0)
    LOADM(bf0,  8) MATVEC(bf1)
    LOADM(bf1,  9) MATVEC(bf2)
    LOADM(bf2, 10) MATVEC(bf3)
    LOADM(bf3, 11) MATVEC(bf0)
    LOADM(bf0, 12) MATVEC(bf1)
    LOADM(bf1, 13) MATVEC(bf2)
    LOADM(bf2, 14) MATVEC(bf3)
    LOADM(bf3, 15) MATVEC(bf0)
    MATVEC(bf1)
    MATVEC(bf2)
    MATVEC(bf3)
#undef LOADM
#undef MATVEC

    float z = (lane < 52) ? v * ws[OFF_ESTOP + lane] : 0.f;
#pragma unroll
    for (int o = 32; o >= 1; o >>= 1) z += __shfl_xor(z, o, 64);
    float logZ = logf(z) + (float)(S + 6 * (len - 1)) * 0.6931471805599453f;

    const int* tg = tags + (size_t)b * TT;
    const float* fb = ws + OFF_FEATS + (size_t)b * TT * CC;
    float g = 0.f;
    for (int t = lane; t < TT; t += 64) {
        if (t < len) {
            int ct = tg[t];
            g += fb[(size_t)t * CC + ct];
            if (t + 1 < len) g += trans[ct * CC + tg[t + 1]];
        }
    }
#pragma unroll
    for (int o = 32; o >= 1; o >>= 1) g += __shfl_xor(g, o, 64);

    unsigned old = 0;
    if (lane == 0) {
        g += trans[STARTT * CC + tg[0]] + trans[tg[len - 1] * CC + STOPP];
        ws[OFF_LOSS + b] = logZ - g;
        __threadfence();
        unsigned* lcnt = (unsigned*)(ws + OFF_RED);
        old = __hip_atomic_fetch_add(lcnt, 1u, __ATOMIC_ACQ_REL, __HIP_MEMORY_SCOPE_AGENT);
    }
    old = (unsigned)__shfl((int)old, 0, 64);
    if (old == BB - 1) {
        __threadfence();
        float tv = (lane < BB) ? ((volatile float*)(ws + OFF_LOSS))[lane] : 0.f;
#pragma unroll
        for (int o = 32; o >= 1; o >>= 1) tv += __shfl_xor(tv, o, 64);
        if (lane == 0) out[0] = tv;
    }
}

extern "C" void kernel_launch(void* const* d_in, const int* in_sizes, int n_in,
                              void* d_out, int out_size, void* d_ws, size_t ws_size,
                              hipStream_t stream)
{
    const float* enc    = (const float*)d_in[0];
    const float* fc_W1  = (const float*)d_in[1];
    const float* fc_b1  = (const float*)d_in[2];
    const float* fc_W2  = (const float*)d_in[3];
    const float* fc_b2  = (const float*)d_in[4];
    const float* trans  = (const float*)d_in[5];
    const float* arg_W1 = (const float*)d_in[6];
    const float* arg_b1 = (const float*)d_in[7];
    const float* arg_W2 = (const float*)d_in[8];
    const float* arg_b2 = (const float*)d_in[9];
    const int* tags     = (const int*)d_in[10];
    const int* lengths  = (const int*)d_in[11];
    const int* tstarts  = (const int*)d_in[12];
    const int* tends    = (const int*)d_in[13];
    const int* tmask    = (const int*)d_in[14];
    const int* estarts  = (const int*)d_in[15];
    const int* eends    = (const int*)d_in[16];
    const int* emask    = (const int*)d_in[17];
    float* out = (float*)d_out;
    float* ws  = (float*)d_ws;

    hipLaunchKernelGGL(k1_prep_span, dim3(1450), dim3(256), 0, stream,
                       enc, fc_W1, fc_b1, fc_W2, fc_b2, trans,
                       arg_W1, arg_b1, arg_W2, arg_b2,
                       tstarts, tends, estarts, eends, ws);
    hipLaunchKernelGGL(k2_fused, dim3(768), dim3(256), 0, stream,
                       enc, lengths, ws);
    hipLaunchKernelGGL(k3_final, dim3(896), dim3(256), 0, stream,
                       trans, tags, lengths, tmask, emask, ws, out);
}